// Round 1
// 402.178 us; speedup vs baseline: 1.2603x; 1.2603x over previous
//
#include <hip/hip_runtime.h>
#include <cstdint>
#include <cmath>

// Round-9: flash_attn v4 -- fragment-linear LDS for K, V^T and P so every
// MFMA fragment read is ds_read_b128 at (base + lane*16): zero bank
// conflicts by construction. Staging via global_load_lds width=16 with
// pre-permuted per-lane global addresses (linear LDS dest). KVBLK=64,
// deferred l-reduction (epilogue only), defer-max rescale (THR=8, log2
// domain), exp2-domain softmax, setprio around MFMA clusters.
//
// B=2, T=2048, D=2048, H=16, G=4, DK=128. f32 in / f32 out.
// ws (54.6 MB): xb/y [4096x2048] | WT(->WoT+VtG) [3072x2048] | qkv [4096x3072]

#define GLOBAL_AS __attribute__((address_space(1)))
#define LDS_AS __attribute__((address_space(3)))

typedef __bf16 bf16x8 __attribute__((ext_vector_type(8)));
typedef __bf16 bf16x4 __attribute__((ext_vector_type(4)));
typedef float f32x4 __attribute__((ext_vector_type(4)));

constexpr int Tn = 2048;

__device__ __forceinline__ f32x4 mfma_bf16(bf16x8 a, bf16x8 b, f32x4 c) {
  return __builtin_amdgcn_mfma_f32_16x16x32_bf16(a, b, c, 0, 0, 0);
}

// ---------------------------------------------------------------- convert f32 -> bf16
__global__ __launch_bounds__(256) void convert_f32_bf16(const float* __restrict__ src,
                                                        __bf16* __restrict__ dst,
                                                        size_t n4) {
  const size_t i = (size_t)blockIdx.x * 256 + threadIdx.x;
  if (i >= n4) return;
  const f32x4 v = ((const f32x4*)src)[i];
  bf16x4 o;
#pragma unroll
  for (int k = 0; k < 4; ++k) o[k] = (__bf16)v[k];
  ((bf16x4*)dst)[i] = o;
}

// ---------------------------------------------------------------- transpose+convert
__global__ __launch_bounds__(256) void transpose_f32_bf16(const float* __restrict__ src,
                                                          __bf16* __restrict__ dst,
                                                          int K, int N) {
  __shared__ __bf16 tile[32][33];
  const int n0 = blockIdx.x * 32, k0 = blockIdx.y * 32;
  const int tx = threadIdx.x, ty = threadIdx.y;
#pragma unroll
  for (int i = 0; i < 32; i += 8)
    tile[ty + i][tx] = (__bf16)src[(size_t)(k0 + ty + i) * N + n0 + tx];
  __syncthreads();
#pragma unroll
  for (int i = 0; i < 32; i += 8)
    dst[(size_t)(n0 + ty + i) * K + k0 + tx] = tile[tx][ty + i];
}

// ---------------------------------------------------------------- transpose V (bf16)
// qkv V-slice [key][dim] -> VtG[(b*4+g)][dim][key] (stride Tn).
__global__ __launch_bounds__(256) void transpose_v(const __bf16* __restrict__ qkv,
                                                   __bf16* __restrict__ vtg) {
  __shared__ __bf16 tile[32][33];
  const int bg = blockIdx.z;
  const int b = bg >> 2, g = bg & 3;
  const int key0 = blockIdx.x * 32, d0 = blockIdx.y * 32;
  const int tx = threadIdx.x, ty = threadIdx.y;
  const __bf16* src = qkv + (size_t)b * Tn * 3072 + 2560 + g * 128;
  __bf16* dst = vtg + (size_t)bg * 128 * Tn;
#pragma unroll
  for (int i = 0; i < 32; i += 8)
    tile[ty + i][tx] = src[(size_t)(key0 + ty + i) * 3072 + d0 + tx];
  __syncthreads();
#pragma unroll
  for (int i = 0; i < 32; i += 8)
    dst[(size_t)(d0 + ty + i) * Tn + key0 + tx] = tile[tx][ty + i];
}

// ---------------------------------------------------------------- GEMM (B^T)
__global__ __launch_bounds__(256) void gemm_bt(const __bf16* __restrict__ A,
                                               const __bf16* __restrict__ BT,
                                               void* __restrict__ C,
                                               int K, int ldc, int outf32) {
  __shared__ __attribute__((aligned(16))) __bf16 As[128 * 32];
  __shared__ __attribute__((aligned(16))) __bf16 Bs[128 * 32];
  const int tid = threadIdx.x;
  const int wave = tid >> 6, lane = tid & 63;
  const int lr = lane & 15, lq = lane >> 4;
  const int wm = wave >> 1, wn = wave & 1;
  const int m0 = blockIdx.y * 128, n0 = blockIdx.x * 128;

  f32x4 acc[4][4] = {};

  const int srow = tid >> 2;
  const int scol = (tid & 3) * 8;
  const __bf16* ga = A + (size_t)(m0 + srow) * K + scol;
  const __bf16* gb = BT + (size_t)(n0 + srow) * K + scol;

  for (int kt = 0; kt < K; kt += 32) {
    __syncthreads();
#pragma unroll
    for (int it = 0; it < 2; ++it) {
      __builtin_amdgcn_global_load_lds((GLOBAL_AS void*)(ga + (size_t)it * 64 * K + kt),
                                       (LDS_AS void*)(As + it * 2048 + wave * 512), 16, 0, 0);
      __builtin_amdgcn_global_load_lds((GLOBAL_AS void*)(gb + (size_t)it * 64 * K + kt),
                                       (LDS_AS void*)(Bs + it * 2048 + wave * 512), 16, 0, 0);
    }
    __syncthreads();

    bf16x8 af[4], bfv[4];
#pragma unroll
    for (int i = 0; i < 4; ++i)
      af[i] = *(const bf16x8*)(As + (wm * 64 + i * 16 + lr) * 32 + lq * 8);
#pragma unroll
    for (int j = 0; j < 4; ++j)
      bfv[j] = *(const bf16x8*)(Bs + (wn * 64 + j * 16 + lr) * 32 + lq * 8);
#pragma unroll
    for (int i = 0; i < 4; ++i)
#pragma unroll
      for (int j = 0; j < 4; ++j)
        acc[i][j] = mfma_bf16(af[i], bfv[j], acc[i][j]);
  }

#pragma unroll
  for (int i = 0; i < 4; ++i) {
    const int row = m0 + wm * 64 + i * 16 + lq * 4;
#pragma unroll
    for (int j = 0; j < 4; ++j) {
      const int col = n0 + wn * 64 + j * 16 + lr;
#pragma unroll
      for (int r = 0; r < 4; ++r) {
        if (outf32)
          ((float*)C)[(size_t)(row + r) * ldc + col] = acc[i][j][r];
        else
          ((__bf16*)C)[(size_t)(row + r) * ldc + col] = (__bf16)acc[i][j][r];
      }
    }
  }
}

// ---------------------------------------------------------------- RoPE
__global__ __launch_bounds__(256) void rope_kernel(__bf16* __restrict__ qkv) {
  const int row = blockIdx.x;
  const int t = row & (Tn - 1);
  for (int p = threadIdx.x; p < 1280; p += 256) {
    const int d = p & 63;
    const int hh = p >> 6;
    const int col = (hh < 16) ? (hh * 128 + d) : (2048 + (hh - 16) * 128 + d);
    const float inv = exp2f((float)d * (-13.287712379549449f / 64.f));
    const float ang = (float)t * inv;
    float sn, cs;
    __sincosf(ang, &sn, &cs);
    __bf16* ptr = qkv + (size_t)row * 3072 + col;
    const float x1 = (float)ptr[0];
    const float x2 = (float)ptr[64];
    ptr[0] = (__bf16)(x1 * cs - x2 * sn);
    ptr[64] = (__bf16)(x2 * cs + x1 * sn);
  }
}

// ---------------------------------------------------------------- flash attention v4
// grid: (T/64, B*H), q-blocks REVERSED (longest first). 4 waves/block.
// KVBLK=64. Fragment-linear LDS: chunk c of Ks holds
//   K[key = (c>>8)*16 + (c&15)][dim = ((c>>6)&3)*32 + ((c>>4)&3)*8 .. +8]
// so a wave's B-fragment read for (sub,f) is Ks + ((sub*4+f)*64+lane)*16 B
// -- contiguous 1 KiB, zero bank conflicts. Same scheme for V^T and P.
// Staged with global_load_lds(16B): linear LDS dest = base + lane*16,
// per-lane pre-permuted global source (64B-contiguous per 4 lanes).
constexpr int KVB = 64;
__global__ __launch_bounds__(256, 4) void flash_attn(const __bf16* __restrict__ qkv,
                                                     const __bf16* __restrict__ vtg,
                                                     __bf16* __restrict__ y) {
  const int b = blockIdx.y >> 4, h = blockIdx.y & 15;
  const int g = h >> 2;
  const int q0 = ((int)gridDim.x - 1 - (int)blockIdx.x) * 64;  // longest blocks first
  const int tid = threadIdx.x;
  const int wave = tid >> 6, lane = tid & 63;
  const int lr = lane & 15, lq = lane >> 4;

  const __bf16* Qb = qkv + (size_t)b * Tn * 3072 + h * 128;
  const __bf16* Kb = qkv + (size_t)b * Tn * 3072 + 2048 + g * 128;
  const __bf16* Vt = vtg + (size_t)(b * 4 + g) * 128 * Tn;  // [dim][key]

  __shared__ __attribute__((aligned(16))) __bf16 Ks[8192];     // 16 KB, frag-linear
  __shared__ __attribute__((aligned(16))) __bf16 Vs[8192];     // 16 KB, frag-linear
  __shared__ __attribute__((aligned(16))) __bf16 Pl[4][1024];  // 2 KB/wave, frag-linear

  // staging: instruction i of wave w fills chunks [i*256 + w*64, +64).
  // K: chunk n -> key kt + (n>>8)*16 + (n&15), dims ((n>>6)&3)*32 + ((n>>4)&3)*8
  //    => per (w,i): key = kt + i*16 + lr, dim = w*32 + lq*8
  // V: chunk m -> dim ((m>>7))*16 + (m&15), keys ((m>>6)&1)*32 + ((m>>4)&3)*8
  //    => per (w,i): dim = (i*2 + (w>>1))*16 + lr, key = kt + (w&1)*32 + lq*8
  const __bf16* ksrc[4];
  const __bf16* vsrc[4];
#pragma unroll
  for (int i = 0; i < 4; ++i) {
    ksrc[i] = Kb + (size_t)(i * 16 + lr) * 3072 + wave * 32 + lq * 8;
    vsrc[i] = Vt + (size_t)((i * 2 + (wave >> 1)) * 16 + lr) * Tn + (wave & 1) * 32 + lq * 8;
  }

  // Q tile, A-operand layout (held in registers for the whole block)
  const int qrow = q0 + wave * 16 + lr;
  bf16x8 qf[4];
#pragma unroll
  for (int f = 0; f < 4; ++f)
    qf[f] = *(const bf16x8*)(Qb + (size_t)qrow * 3072 + f * 32 + lq * 8);

  f32x4 o[8] = {};
  float m_i[4], l_i[4];
#pragma unroll
  for (int r = 0; r < 4; ++r) { m_i[r] = -1e30f; l_i[r] = 0.f; }
  const float kscale = 0.12752909695983215f;  // (1/sqrt(128)) * log2(e)

  __bf16* Plw = &Pl[wave][0];
  const int lr7 = lr & 7, lrh = lr >> 3;
  const int pbase = lq * 32 + lr7;

  for (int kt = 0; kt < q0 + 64; kt += KVB) {
    __syncthreads();  // prev-iter LDS reads done
#pragma unroll
    for (int i = 0; i < 4; ++i) {
      __builtin_amdgcn_global_load_lds((GLOBAL_AS void*)ksrc[i],
                                       (LDS_AS void*)(Ks + (i * 256 + wave * 64) * 8), 16, 0, 0);
      __builtin_amdgcn_global_load_lds((GLOBAL_AS void*)vsrc[i],
                                       (LDS_AS void*)(Vs + (i * 256 + wave * 64) * 8), 16, 0, 0);
      ksrc[i] += (size_t)KVB * 3072;
      vsrc[i] += KVB;
    }
    __syncthreads();  // implicit vmcnt(0) drain -> tiles visible

    // S = Q K^T : four 16-key subtiles, fragments at (base + lane*16)
    f32x4 s[4] = {};
    __builtin_amdgcn_s_setprio(1);
#pragma unroll
    for (int sub = 0; sub < 4; ++sub)
#pragma unroll
      for (int f = 0; f < 4; ++f) {
        const bf16x8 kf = *(const bf16x8*)(Ks + ((sub * 4 + f) * 64 + lane) * 8);
        s[sub] = mfma_bf16(qf[f], kf, s[sub]);
      }
    __builtin_amdgcn_s_setprio(0);

    // online softmax, log2 domain. Row = lq*4+r, key cols = c*16 + lr.
    const bool full = (kt + KVB - 1) <= (q0 + wave * 16);  // wave-uniform
    float mx[4];
    bool need = false;
#pragma unroll
    for (int r = 0; r < 4; ++r) {
      if (full) {
#pragma unroll
        for (int c = 0; c < 4; ++c) s[c][r] = s[c][r] * kscale;
      } else {
        const int q = q0 + wave * 16 + lq * 4 + r;
#pragma unroll
        for (int c = 0; c < 4; ++c)
          s[c][r] = (kt + c * 16 + lr <= q) ? s[c][r] * kscale : -1e30f;
      }
      float m = fmaxf(fmaxf(s[0][r], s[1][r]), fmaxf(s[2][r], s[3][r]));
      m = fmaxf(m, __shfl_xor(m, 1));
      m = fmaxf(m, __shfl_xor(m, 2));
      m = fmaxf(m, __shfl_xor(m, 4));
      m = fmaxf(m, __shfl_xor(m, 8));
      mx[r] = m;
      need = need || (m > m_i[r] + 8.f);
    }
    if (__any(need)) {  // defer-max: rescale only when a row max grew by >8
#pragma unroll
      for (int r = 0; r < 4; ++r) {
        const float mnew = fmaxf(m_i[r], mx[r]);
        const float alpha = __builtin_amdgcn_exp2f(m_i[r] - mnew);
        m_i[r] = mnew;
        l_i[r] *= alpha;
#pragma unroll
        for (int n = 0; n < 8; ++n) o[n][r] *= alpha;
      }
    }
    // P = 2^(s - m), bounded by 2^8; l kept as per-lane partial (no tree).
    // P chunk (c>>1)*64 + ((c&1)*2 + lr>>3)*16 + row, byte (lr&7)*2.
#pragma unroll
    for (int r = 0; r < 4; ++r) {
#pragma unroll
      for (int c = 0; c < 4; ++c) {
        const float pv = __builtin_amdgcn_exp2f(s[c][r] - m_i[r]);
        l_i[r] += pv;
        Plw[(c >> 1) * 512 + ((c & 1) * 2 + lrh) * 128 + pbase + r * 8] = (__bf16)pv;
      }
    }

    __threadfence_block();  // Pl is wave-private; order write->read

    const bf16x8 pa0 = *(const bf16x8*)(Plw + lane * 8);          // k = 0..31
    const bf16x8 pa1 = *(const bf16x8*)(Plw + (64 + lane) * 8);   // k = 32..63
    __builtin_amdgcn_s_setprio(1);
#pragma unroll
    for (int n = 0; n < 8; ++n) {
      const bf16x8 v0 = *(const bf16x8*)(Vs + ((n * 2 + 0) * 64 + lane) * 8);
      const bf16x8 v1 = *(const bf16x8*)(Vs + ((n * 2 + 1) * 64 + lane) * 8);
      o[n] = mfma_bf16(pa0, v0, o[n]);
      o[n] = mfma_bf16(pa1, v1, o[n]);
    }
    __builtin_amdgcn_s_setprio(0);
  }

  // epilogue: deferred l reduction, then normalize + store
#pragma unroll
  for (int r = 0; r < 4; ++r) {
    float l = l_i[r];
    l += __shfl_xor(l, 1);
    l += __shfl_xor(l, 2);
    l += __shfl_xor(l, 4);
    l += __shfl_xor(l, 8);
    const float inv = 1.0f / l;
    const int q = q0 + wave * 16 + lq * 4 + r;
#pragma unroll
    for (int n = 0; n < 8; ++n)
      y[(size_t)(b * Tn + q) * 2048 + h * 128 + n * 16 + lr] = (__bf16)(o[n][r] * inv);
  }
}

// ---------------------------------------------------------------- launch
extern "C" void kernel_launch(void* const* d_in, const int* in_sizes, int n_in,
                              void* d_out, int out_size, void* d_ws, size_t ws_size,
                              hipStream_t stream) {
  (void)in_sizes; (void)n_in; (void)out_size; (void)ws_size;
  const float* x  = (const float*)d_in[0];
  const float* Wq = (const float*)d_in[1];
  const float* Wk = (const float*)d_in[2];
  const float* Wv = (const float*)d_in[3];
  const float* Wo = (const float*)d_in[4];
  float* out = (float*)d_out;

  __bf16* xb  = (__bf16*)d_ws;                  // [4096][2048]; y aliases after gemm1
  __bf16* y   = xb;
  __bf16* WT  = xb + (size_t)4096 * 2048;       // [3072][2048]
  __bf16* WoT = WT;                             // [2048][2048] aliases after gemm1
  __bf16* VtG = WT + (size_t)2048 * 2048;       // [8][128][2048]
  __bf16* qkv = WT + (size_t)3072 * 2048;       // [4096][3072]

  convert_f32_bf16<<<(4096 * 2048 / 4 + 255) / 256, 256, 0, stream>>>(x, xb, 4096 * 2048 / 4);
  dim3 tb(32, 8);
  transpose_f32_bf16<<<dim3(64, 64), tb, 0, stream>>>(Wq, WT, 2048, 2048);
  transpose_f32_bf16<<<dim3(16, 64), tb, 0, stream>>>(Wk, WT + (size_t)2048 * 2048, 2048, 512);
  transpose_f32_bf16<<<dim3(16, 64), tb, 0, stream>>>(Wv, WT + (size_t)2560 * 2048, 2048, 512);

  gemm_bt<<<dim3(3072 / 128, 4096 / 128), 256, 0, stream>>>(xb, WT, qkv, 2048, 3072, 0);
  rope_kernel<<<4096, 256, 0, stream>>>(qkv);

  transpose_v<<<dim3(Tn / 32, 4, 8), tb, 0, stream>>>(qkv, VtG);
  transpose_f32_bf16<<<dim3(64, 64), tb, 0, stream>>>(Wo, WoT, 2048, 2048);

  flash_attn<<<dim3(Tn / 64, 2 * 16), 256, 0, stream>>>(qkv, VtG, y);
  gemm_bt<<<dim3(2048 / 128, 4096 / 128), 256, 0, stream>>>(y, WoT, out, 2048, 2048, 1);
}

// Round 2
// 388.887 us; speedup vs baseline: 1.3034x; 1.0342x over previous
//
#include <hip/hip_runtime.h>
#include <cstdint>
#include <cmath>

// Round-10: flash_attn v5 -- QBLK=128 (8 waves), double-buffered K/V tiles,
// minimum 2-phase schedule: stage(next tile) issued BEFORE compute(current),
// ONE barrier per tile (its implicit vmcnt(0) drain lands after the whole
// QK+softmax+PV phase has covered the load latency). Fragment-linear LDS
// everywhere (zero-conflict ds_read_b128 at base+lane*16), per-wave skip of
// fully-masked causal tiles. Everything else unchanged from round 9.
//
// B=2, T=2048, D=2048, H=16, G=4, DK=128. f32 in / f32 out.
// ws (54.6 MB): xb/y [4096x2048] | WT(->WoT+VtG) [3072x2048] | qkv [4096x3072]

#define GLOBAL_AS __attribute__((address_space(1)))
#define LDS_AS __attribute__((address_space(3)))

typedef __bf16 bf16x8 __attribute__((ext_vector_type(8)));
typedef __bf16 bf16x4 __attribute__((ext_vector_type(4)));
typedef float f32x4 __attribute__((ext_vector_type(4)));

constexpr int Tn = 2048;

__device__ __forceinline__ f32x4 mfma_bf16(bf16x8 a, bf16x8 b, f32x4 c) {
  return __builtin_amdgcn_mfma_f32_16x16x32_bf16(a, b, c, 0, 0, 0);
}

// ---------------------------------------------------------------- convert f32 -> bf16
__global__ __launch_bounds__(256) void convert_f32_bf16(const float* __restrict__ src,
                                                        __bf16* __restrict__ dst,
                                                        size_t n4) {
  const size_t i = (size_t)blockIdx.x * 256 + threadIdx.x;
  if (i >= n4) return;
  const f32x4 v = ((const f32x4*)src)[i];
  bf16x4 o;
#pragma unroll
  for (int k = 0; k < 4; ++k) o[k] = (__bf16)v[k];
  ((bf16x4*)dst)[i] = o;
}

// ---------------------------------------------------------------- transpose+convert
__global__ __launch_bounds__(256) void transpose_f32_bf16(const float* __restrict__ src,
                                                          __bf16* __restrict__ dst,
                                                          int K, int N) {
  __shared__ __bf16 tile[32][33];
  const int n0 = blockIdx.x * 32, k0 = blockIdx.y * 32;
  const int tx = threadIdx.x, ty = threadIdx.y;
#pragma unroll
  for (int i = 0; i < 32; i += 8)
    tile[ty + i][tx] = (__bf16)src[(size_t)(k0 + ty + i) * N + n0 + tx];
  __syncthreads();
#pragma unroll
  for (int i = 0; i < 32; i += 8)
    dst[(size_t)(n0 + ty + i) * K + k0 + tx] = tile[tx][ty + i];
}

// ---------------------------------------------------------------- transpose V (bf16)
// qkv V-slice [key][dim] -> VtG[(b*4+g)][dim][key] (stride Tn).
__global__ __launch_bounds__(256) void transpose_v(const __bf16* __restrict__ qkv,
                                                   __bf16* __restrict__ vtg) {
  __shared__ __bf16 tile[32][33];
  const int bg = blockIdx.z;
  const int b = bg >> 2, g = bg & 3;
  const int key0 = blockIdx.x * 32, d0 = blockIdx.y * 32;
  const int tx = threadIdx.x, ty = threadIdx.y;
  const __bf16* src = qkv + (size_t)b * Tn * 3072 + 2560 + g * 128;
  __bf16* dst = vtg + (size_t)bg * 128 * Tn;
#pragma unroll
  for (int i = 0; i < 32; i += 8)
    tile[ty + i][tx] = src[(size_t)(key0 + ty + i) * 3072 + d0 + tx];
  __syncthreads();
#pragma unroll
  for (int i = 0; i < 32; i += 8)
    dst[(size_t)(d0 + ty + i) * Tn + key0 + tx] = tile[tx][ty + i];
}

// ---------------------------------------------------------------- GEMM (B^T)
__global__ __launch_bounds__(256) void gemm_bt(const __bf16* __restrict__ A,
                                               const __bf16* __restrict__ BT,
                                               void* __restrict__ C,
                                               int K, int ldc, int outf32) {
  __shared__ __attribute__((aligned(16))) __bf16 As[128 * 32];
  __shared__ __attribute__((aligned(16))) __bf16 Bs[128 * 32];
  const int tid = threadIdx.x;
  const int wave = tid >> 6, lane = tid & 63;
  const int lr = lane & 15, lq = lane >> 4;
  const int wm = wave >> 1, wn = wave & 1;
  const int m0 = blockIdx.y * 128, n0 = blockIdx.x * 128;

  f32x4 acc[4][4] = {};

  const int srow = tid >> 2;
  const int scol = (tid & 3) * 8;
  const __bf16* ga = A + (size_t)(m0 + srow) * K + scol;
  const __bf16* gb = BT + (size_t)(n0 + srow) * K + scol;

  for (int kt = 0; kt < K; kt += 32) {
    __syncthreads();
#pragma unroll
    for (int it = 0; it < 2; ++it) {
      __builtin_amdgcn_global_load_lds((GLOBAL_AS void*)(ga + (size_t)it * 64 * K + kt),
                                       (LDS_AS void*)(As + it * 2048 + wave * 512), 16, 0, 0);
      __builtin_amdgcn_global_load_lds((GLOBAL_AS void*)(gb + (size_t)it * 64 * K + kt),
                                       (LDS_AS void*)(Bs + it * 2048 + wave * 512), 16, 0, 0);
    }
    __syncthreads();

    bf16x8 af[4], bfv[4];
#pragma unroll
    for (int i = 0; i < 4; ++i)
      af[i] = *(const bf16x8*)(As + (wm * 64 + i * 16 + lr) * 32 + lq * 8);
#pragma unroll
    for (int j = 0; j < 4; ++j)
      bfv[j] = *(const bf16x8*)(Bs + (wn * 64 + j * 16 + lr) * 32 + lq * 8);
#pragma unroll
    for (int i = 0; i < 4; ++i)
#pragma unroll
      for (int j = 0; j < 4; ++j)
        acc[i][j] = mfma_bf16(af[i], bfv[j], acc[i][j]);
  }

#pragma unroll
  for (int i = 0; i < 4; ++i) {
    const int row = m0 + wm * 64 + i * 16 + lq * 4;
#pragma unroll
    for (int j = 0; j < 4; ++j) {
      const int col = n0 + wn * 64 + j * 16 + lr;
#pragma unroll
      for (int r = 0; r < 4; ++r) {
        if (outf32)
          ((float*)C)[(size_t)(row + r) * ldc + col] = acc[i][j][r];
        else
          ((__bf16*)C)[(size_t)(row + r) * ldc + col] = (__bf16)acc[i][j][r];
      }
    }
  }
}

// ---------------------------------------------------------------- RoPE
__global__ __launch_bounds__(256) void rope_kernel(__bf16* __restrict__ qkv) {
  const int row = blockIdx.x;
  const int t = row & (Tn - 1);
  for (int p = threadIdx.x; p < 1280; p += 256) {
    const int d = p & 63;
    const int hh = p >> 6;
    const int col = (hh < 16) ? (hh * 128 + d) : (2048 + (hh - 16) * 128 + d);
    const float inv = exp2f((float)d * (-13.287712379549449f / 64.f));
    const float ang = (float)t * inv;
    float sn, cs;
    __sincosf(ang, &sn, &cs);
    __bf16* ptr = qkv + (size_t)row * 3072 + col;
    const float x1 = (float)ptr[0];
    const float x2 = (float)ptr[64];
    ptr[0] = (__bf16)(x1 * cs - x2 * sn);
    ptr[64] = (__bf16)(x2 * cs + x1 * sn);
  }
}

// ---------------------------------------------------------------- flash attention v5
// grid: (T/128, B*H), q-blocks REVERSED (longest first). 8 waves/block.
// KVB=64, double-buffered Ks/Vs, 2-phase schedule (one barrier per tile).
// Fragment-linear LDS chunks (16B chunk c):
//   Ks: c -> K[key (c>>8)*16 + (c&15)][dim ((c>>6)&3)*32 + ((c>>4)&3)*8 ..+8]
//   Vs: c -> V^T[dim (c>>7)*16 + (c&15)][key ((c>>6)&1)*32 + ((c>>4)&3)*8 ..+8]
// so every MFMA fragment read is ds_read_b128 at (base + lane*16): conflict-free.
// Staging: global_load_lds(16B), linear LDS dest = wave-uniform base + lane*16,
// per-lane pre-permuted global source (64B-contiguous per 4 lanes).
constexpr int KVB = 64;
__global__ __launch_bounds__(512, 4) void flash_attn(const __bf16* __restrict__ qkv,
                                                     const __bf16* __restrict__ vtg,
                                                     __bf16* __restrict__ y) {
  const int b = blockIdx.y >> 4, h = blockIdx.y & 15;
  const int g = h >> 2;
  const int q0 = ((int)gridDim.x - 1 - (int)blockIdx.x) * 128;  // longest blocks first
  const int tid = threadIdx.x;
  const int wave = tid >> 6, lane = tid & 63;
  const int lr = lane & 15, lq = lane >> 4;

  const __bf16* Qb = qkv + (size_t)b * Tn * 3072 + h * 128;
  const __bf16* Kb = qkv + (size_t)b * Tn * 3072 + 2048 + g * 128;
  const __bf16* Vt = vtg + (size_t)(b * 4 + g) * 128 * Tn;  // [dim][key]

  __shared__ __attribute__((aligned(16))) __bf16 Ks[2][8192];  // 2 x 16 KB
  __shared__ __attribute__((aligned(16))) __bf16 Vs[2][8192];  // 2 x 16 KB
  __shared__ __attribute__((aligned(16))) __bf16 Pl[8][1024];  // 2 KB/wave

  // staging: instruction i (0..1) of wave w fills chunks [i*512 + w*64, +64):
  //   K: key = kt + (i*2 + (w>>2))*16 + lr, dim = (w&3)*32 + lq*8
  //   V: dim = (i*4 + (w>>1))*16 + lr,      key = kt + (w&1)*32 + lq*8
  const __bf16* ksrc[2];
  const __bf16* vsrc[2];
#pragma unroll
  for (int i = 0; i < 2; ++i) {
    ksrc[i] = Kb + (size_t)((i * 2 + (wave >> 2)) * 16 + lr) * 3072 + (wave & 3) * 32 + lq * 8;
    vsrc[i] = Vt + (size_t)((i * 4 + (wave >> 1)) * 16 + lr) * Tn + (wave & 1) * 32 + lq * 8;
  }

  // Q tile, A-operand layout (held in registers for the whole block)
  const int qrow = q0 + wave * 16 + lr;
  bf16x8 qf[4];
#pragma unroll
  for (int f = 0; f < 4; ++f)
    qf[f] = *(const bf16x8*)(Qb + (size_t)qrow * 3072 + f * 32 + lq * 8);

  f32x4 o[8] = {};
  float m_i[4], l_i[4];
#pragma unroll
  for (int r = 0; r < 4; ++r) { m_i[r] = -1e30f; l_i[r] = 0.f; }
  const float kscale = 0.12752909695983215f;  // (1/sqrt(128)) * log2(e)

  __bf16* Plw = &Pl[wave][0];
  const int lr7 = lr & 7, lrh = lr >> 3;
  const int pbase = lq * 32 + lr7;

  // ---- prologue: stage tile 0 into buffer 0; barrier drains vmcnt(0)
#pragma unroll
  for (int i = 0; i < 2; ++i) {
    __builtin_amdgcn_global_load_lds((GLOBAL_AS void*)ksrc[i],
                                     (LDS_AS void*)(&Ks[0][(i * 512 + wave * 64) * 8]), 16, 0, 0);
    __builtin_amdgcn_global_load_lds((GLOBAL_AS void*)vsrc[i],
                                     (LDS_AS void*)(&Vs[0][(i * 512 + wave * 64) * 8]), 16, 0, 0);
    ksrc[i] += (size_t)KVB * 3072;
    vsrc[i] += KVB;
  }
  __syncthreads();

  const int ktend = q0 + 128;
  int cur = 0;
  for (int kt = 0; kt < ktend; kt += KVB) {
    // ---- issue next-tile staging into the other buffer (overlaps compute)
    if (kt + KVB < ktend) {
#pragma unroll
      for (int i = 0; i < 2; ++i) {
        __builtin_amdgcn_global_load_lds(
            (GLOBAL_AS void*)ksrc[i],
            (LDS_AS void*)(&Ks[cur ^ 1][(i * 512 + wave * 64) * 8]), 16, 0, 0);
        __builtin_amdgcn_global_load_lds(
            (GLOBAL_AS void*)vsrc[i],
            (LDS_AS void*)(&Vs[cur ^ 1][(i * 512 + wave * 64) * 8]), 16, 0, 0);
        ksrc[i] += (size_t)KVB * 3072;
        vsrc[i] += KVB;
      }
    }

    // ---- per-wave skip of fully-masked causal tiles (wave-uniform)
    const bool active = kt <= q0 + wave * 16 + 15;
    if (active) {
      // S = Q K^T : four 16-key subtiles, fragments at (base + lane*16)
      f32x4 s[4] = {};
      __builtin_amdgcn_s_setprio(1);
#pragma unroll
      for (int sub = 0; sub < 4; ++sub)
#pragma unroll
        for (int f = 0; f < 4; ++f) {
          const bf16x8 kf = *(const bf16x8*)(&Ks[cur][((sub * 4 + f) * 64 + lane) * 8]);
          s[sub] = mfma_bf16(qf[f], kf, s[sub]);
        }
      __builtin_amdgcn_s_setprio(0);

      // online softmax, log2 domain. Row = lq*4+r, key cols = c*16 + lr.
      const bool full = (kt + KVB - 1) <= (q0 + wave * 16);  // wave-uniform
      float mx[4];
      bool need = false;
#pragma unroll
      for (int r = 0; r < 4; ++r) {
        if (full) {
#pragma unroll
          for (int c = 0; c < 4; ++c) s[c][r] = s[c][r] * kscale;
        } else {
          const int q = q0 + wave * 16 + lq * 4 + r;
#pragma unroll
          for (int c = 0; c < 4; ++c)
            s[c][r] = (kt + c * 16 + lr <= q) ? s[c][r] * kscale : -1e30f;
        }
        float m = fmaxf(fmaxf(s[0][r], s[1][r]), fmaxf(s[2][r], s[3][r]));
        m = fmaxf(m, __shfl_xor(m, 1));
        m = fmaxf(m, __shfl_xor(m, 2));
        m = fmaxf(m, __shfl_xor(m, 4));
        m = fmaxf(m, __shfl_xor(m, 8));
        mx[r] = m;
        need = need || (m > m_i[r] + 8.f);
      }
      if (__any(need)) {  // defer-max: rescale only when a row max grew by >8
#pragma unroll
        for (int r = 0; r < 4; ++r) {
          const float mnew = fmaxf(m_i[r], mx[r]);
          const float alpha = __builtin_amdgcn_exp2f(m_i[r] - mnew);
          m_i[r] = mnew;
          l_i[r] *= alpha;
#pragma unroll
          for (int n = 0; n < 8; ++n) o[n][r] *= alpha;
        }
      }
      // P = 2^(s - m), bounded by 2^8; l kept as per-lane partial (no tree).
#pragma unroll
      for (int r = 0; r < 4; ++r) {
#pragma unroll
        for (int c = 0; c < 4; ++c) {
          const float pv = __builtin_amdgcn_exp2f(s[c][r] - m_i[r]);
          l_i[r] += pv;
          Plw[(c >> 1) * 512 + ((c & 1) * 2 + lrh) * 128 + pbase + r * 8] = (__bf16)pv;
        }
      }

      __threadfence_block();  // Pl is wave-private; order write->read

      const bf16x8 pa0 = *(const bf16x8*)(Plw + lane * 8);         // k = 0..31
      const bf16x8 pa1 = *(const bf16x8*)(Plw + (64 + lane) * 8);  // k = 32..63
      __builtin_amdgcn_s_setprio(1);
#pragma unroll
      for (int n = 0; n < 8; ++n) {
        const bf16x8 v0 = *(const bf16x8*)(&Vs[cur][((n * 2 + 0) * 64 + lane) * 8]);
        const bf16x8 v1 = *(const bf16x8*)(&Vs[cur][((n * 2 + 1) * 64 + lane) * 8]);
        o[n] = mfma_bf16(pa0, v0, o[n]);
        o[n] = mfma_bf16(pa1, v1, o[n]);
      }
      __builtin_amdgcn_s_setprio(0);
    }

    // one barrier per tile: implicit vmcnt(0) drain = next tile staged,
    // and all waves done reading buf[cur] before it is overwritten.
    __syncthreads();
    cur ^= 1;
  }

  // epilogue: deferred l reduction, then normalize + store
#pragma unroll
  for (int r = 0; r < 4; ++r) {
    float l = l_i[r];
    l += __shfl_xor(l, 1);
    l += __shfl_xor(l, 2);
    l += __shfl_xor(l, 4);
    l += __shfl_xor(l, 8);
    const float inv = 1.0f / l;
    const int q = q0 + wave * 16 + lq * 4 + r;
#pragma unroll
    for (int n = 0; n < 8; ++n)
      y[(size_t)(b * Tn + q) * 2048 + h * 128 + n * 16 + lr] = (__bf16)(o[n][r] * inv);
  }
}

// ---------------------------------------------------------------- launch
extern "C" void kernel_launch(void* const* d_in, const int* in_sizes, int n_in,
                              void* d_out, int out_size, void* d_ws, size_t ws_size,
                              hipStream_t stream) {
  (void)in_sizes; (void)n_in; (void)out_size; (void)ws_size;
  const float* x  = (const float*)d_in[0];
  const float* Wq = (const float*)d_in[1];
  const float* Wk = (const float*)d_in[2];
  const float* Wv = (const float*)d_in[3];
  const float* Wo = (const float*)d_in[4];
  float* out = (float*)d_out;

  __bf16* xb  = (__bf16*)d_ws;                  // [4096][2048]; y aliases after gemm1
  __bf16* y   = xb;
  __bf16* WT  = xb + (size_t)4096 * 2048;       // [3072][2048]
  __bf16* WoT = WT;                             // [2048][2048] aliases after gemm1
  __bf16* VtG = WT + (size_t)2048 * 2048;       // [8][128][2048]
  __bf16* qkv = WT + (size_t)3072 * 2048;       // [4096][3072]

  convert_f32_bf16<<<(4096 * 2048 / 4 + 255) / 256, 256, 0, stream>>>(x, xb, 4096 * 2048 / 4);
  dim3 tb(32, 8);
  transpose_f32_bf16<<<dim3(64, 64), tb, 0, stream>>>(Wq, WT, 2048, 2048);
  transpose_f32_bf16<<<dim3(16, 64), tb, 0, stream>>>(Wk, WT + (size_t)2048 * 2048, 2048, 512);
  transpose_f32_bf16<<<dim3(16, 64), tb, 0, stream>>>(Wv, WT + (size_t)2560 * 2048, 2048, 512);

  gemm_bt<<<dim3(3072 / 128, 4096 / 128), 256, 0, stream>>>(xb, WT, qkv, 2048, 3072, 0);
  rope_kernel<<<4096, 256, 0, stream>>>(qkv);

  transpose_v<<<dim3(Tn / 32, 4, 8), tb, 0, stream>>>(qkv, VtG);
  transpose_f32_bf16<<<dim3(64, 64), tb, 0, stream>>>(Wo, WoT, 2048, 2048);

  flash_attn<<<dim3(Tn / 128, 2 * 16), 512, 0, stream>>>(qkv, VtG, y);
  gemm_bt<<<dim3(2048 / 128, 4096 / 128), 256, 0, stream>>>(y, WoT, out, 2048, 2048, 1);
}

// Round 4
// 369.838 us; speedup vs baseline: 1.3705x; 1.0515x over previous
//
#include <hip/hip_runtime.h>
#include <cstdint>
#include <cmath>

// Round-12: flash_attn v6b -- v6 with the global_load_lds API fixed: LDS
// destination must be the WAVE-UNIFORM base (HW writes base + lane*16);
// v6 passed a per-lane pointer. Structure unchanged from v6:
// swapped QK^T (S^T = mfma32(K,Q)), 4 waves x 32 q-rows (QBLK=128),
// in-register softmax (ONE shfl_xor(32) per tile), P packed to bf16 and
// redistributed in-register (no LDS round-trip), fragment-linear K/V LDS,
// 2-phase double-buffered staging, one barrier per 64-key tile.
//
// B=2, T=2048, D=2048, H=16, G=4, DK=128. f32 in / f32 out.
// ws (54.6 MB): xb/y [4096x2048] | WT(->WoT+VtG) [3072x2048] | qkv [4096x3072]

#define GLOBAL_AS __attribute__((address_space(1)))
#define LDS_AS __attribute__((address_space(3)))

typedef __bf16 bf16x8 __attribute__((ext_vector_type(8)));
typedef __bf16 bf16x4 __attribute__((ext_vector_type(4)));
typedef float f32x4 __attribute__((ext_vector_type(4)));
typedef float f32x16 __attribute__((ext_vector_type(16)));

constexpr int Tn = 2048;

__device__ __forceinline__ f32x4 mfma_bf16(bf16x8 a, bf16x8 b, f32x4 c) {
  return __builtin_amdgcn_mfma_f32_16x16x32_bf16(a, b, c, 0, 0, 0);
}
__device__ __forceinline__ f32x16 mfma32(bf16x8 a, bf16x8 b, f32x16 c) {
  return __builtin_amdgcn_mfma_f32_32x32x16_bf16(a, b, c, 0, 0, 0);
}
__device__ __forceinline__ uint32_t pack_bf16(float a, float b) {
  union { __bf16 h[2]; uint32_t u; } c;
  c.h[0] = (__bf16)a;
  c.h[1] = (__bf16)b;
  return c.u;
}

// ---------------------------------------------------------------- convert f32 -> bf16
__global__ __launch_bounds__(256) void convert_f32_bf16(const float* __restrict__ src,
                                                        __bf16* __restrict__ dst,
                                                        size_t n4) {
  const size_t i = (size_t)blockIdx.x * 256 + threadIdx.x;
  if (i >= n4) return;
  const f32x4 v = ((const f32x4*)src)[i];
  bf16x4 o;
#pragma unroll
  for (int k = 0; k < 4; ++k) o[k] = (__bf16)v[k];
  ((bf16x4*)dst)[i] = o;
}

// ---------------------------------------------------------------- transpose+convert
__global__ __launch_bounds__(256) void transpose_f32_bf16(const float* __restrict__ src,
                                                          __bf16* __restrict__ dst,
                                                          int K, int N) {
  __shared__ __bf16 tile[32][33];
  const int n0 = blockIdx.x * 32, k0 = blockIdx.y * 32;
  const int tx = threadIdx.x, ty = threadIdx.y;
#pragma unroll
  for (int i = 0; i < 32; i += 8)
    tile[ty + i][tx] = (__bf16)src[(size_t)(k0 + ty + i) * N + n0 + tx];
  __syncthreads();
#pragma unroll
  for (int i = 0; i < 32; i += 8)
    dst[(size_t)(n0 + ty + i) * K + k0 + tx] = tile[tx][ty + i];
}

// ---------------------------------------------------------------- transpose V (bf16)
// qkv V-slice [key][dim] -> VtG[(b*4+g)][dim][key] (stride Tn).
__global__ __launch_bounds__(256) void transpose_v(const __bf16* __restrict__ qkv,
                                                   __bf16* __restrict__ vtg) {
  __shared__ __bf16 tile[32][33];
  const int bg = blockIdx.z;
  const int b = bg >> 2, g = bg & 3;
  const int key0 = blockIdx.x * 32, d0 = blockIdx.y * 32;
  const int tx = threadIdx.x, ty = threadIdx.y;
  const __bf16* src = qkv + (size_t)b * Tn * 3072 + 2560 + g * 128;
  __bf16* dst = vtg + (size_t)bg * 128 * Tn;
#pragma unroll
  for (int i = 0; i < 32; i += 8)
    tile[ty + i][tx] = src[(size_t)(key0 + ty + i) * 3072 + d0 + tx];
  __syncthreads();
#pragma unroll
  for (int i = 0; i < 32; i += 8)
    dst[(size_t)(d0 + ty + i) * Tn + key0 + tx] = tile[tx][ty + i];
}

// ---------------------------------------------------------------- GEMM (B^T)
__global__ __launch_bounds__(256) void gemm_bt(const __bf16* __restrict__ A,
                                               const __bf16* __restrict__ BT,
                                               void* __restrict__ C,
                                               int K, int ldc, int outf32) {
  __shared__ __attribute__((aligned(16))) __bf16 As[128 * 32];
  __shared__ __attribute__((aligned(16))) __bf16 Bs[128 * 32];
  const int tid = threadIdx.x;
  const int wave = tid >> 6, lane = tid & 63;
  const int lr = lane & 15, lq = lane >> 4;
  const int wm = wave >> 1, wn = wave & 1;
  const int m0 = blockIdx.y * 128, n0 = blockIdx.x * 128;

  f32x4 acc[4][4] = {};

  const int srow = tid >> 2;
  const int scol = (tid & 3) * 8;
  const __bf16* ga = A + (size_t)(m0 + srow) * K + scol;
  const __bf16* gb = BT + (size_t)(n0 + srow) * K + scol;

  for (int kt = 0; kt < K; kt += 32) {
    __syncthreads();
#pragma unroll
    for (int it = 0; it < 2; ++it) {
      __builtin_amdgcn_global_load_lds((GLOBAL_AS void*)(ga + (size_t)it * 64 * K + kt),
                                       (LDS_AS void*)(As + it * 2048 + wave * 512), 16, 0, 0);
      __builtin_amdgcn_global_load_lds((GLOBAL_AS void*)(gb + (size_t)it * 64 * K + kt),
                                       (LDS_AS void*)(Bs + it * 2048 + wave * 512), 16, 0, 0);
    }
    __syncthreads();

    bf16x8 af[4], bfv[4];
#pragma unroll
    for (int i = 0; i < 4; ++i)
      af[i] = *(const bf16x8*)(As + (wm * 64 + i * 16 + lr) * 32 + lq * 8);
#pragma unroll
    for (int j = 0; j < 4; ++j)
      bfv[j] = *(const bf16x8*)(Bs + (wn * 64 + j * 16 + lr) * 32 + lq * 8);
#pragma unroll
    for (int i = 0; i < 4; ++i)
#pragma unroll
      for (int j = 0; j < 4; ++j)
        acc[i][j] = mfma_bf16(af[i], bfv[j], acc[i][j]);
  }

#pragma unroll
  for (int i = 0; i < 4; ++i) {
    const int row = m0 + wm * 64 + i * 16 + lq * 4;
#pragma unroll
    for (int j = 0; j < 4; ++j) {
      const int col = n0 + wn * 64 + j * 16 + lr;
#pragma unroll
      for (int r = 0; r < 4; ++r) {
        if (outf32)
          ((float*)C)[(size_t)(row + r) * ldc + col] = acc[i][j][r];
        else
          ((__bf16*)C)[(size_t)(row + r) * ldc + col] = (__bf16)acc[i][j][r];
      }
    }
  }
}

// ---------------------------------------------------------------- RoPE
__global__ __launch_bounds__(256) void rope_kernel(__bf16* __restrict__ qkv) {
  const int row = blockIdx.x;
  const int t = row & (Tn - 1);
  for (int p = threadIdx.x; p < 1280; p += 256) {
    const int d = p & 63;
    const int hh = p >> 6;
    const int col = (hh < 16) ? (hh * 128 + d) : (2048 + (hh - 16) * 128 + d);
    const float inv = exp2f((float)d * (-13.287712379549449f / 64.f));
    const float ang = (float)t * inv;
    float sn, cs;
    __sincosf(ang, &sn, &cs);
    __bf16* ptr = qkv + (size_t)row * 3072 + col;
    const float x1 = (float)ptr[0];
    const float x2 = (float)ptr[64];
    ptr[0] = (__bf16)(x1 * cs - x2 * sn);
    ptr[64] = (__bf16)(x2 * cs + x1 * sn);
  }
}

// ---------------------------------------------------------------- flash attention v6b
// grid: (T/128, B*H), q-blocks REVERSED (longest first). 4 waves x 32 q-rows.
// KVB=64, double-buffered Ks/Vs, 2-phase schedule (one barrier per tile).
// Swapped QK^T: S^T[key][q] = mfma32(A=K-frag, B=Q-frag). 32x32 C/D layout:
// col(lane&31)=q, row=(reg&3)+8*(reg>>2)+4*(lane>>5)=key -> a lane PAIR holds
// all 64 key-scores of one q-row. Softmax: in-lane reduce + one shfl_xor(32).
// PV: O^T[d][q] = mfma32(A=V^T-frag, B=P^T-frag), P assembled in-register.
// Fragment-linear LDS: chunk c (16B) lives at Ks+c*8; HW staging writes
// (uniform base + lane*16) land chunk (base_chunk + lane) -- matches reads.
constexpr int KVB = 64;
__global__ __launch_bounds__(256, 2) void flash_attn(const __bf16* __restrict__ qkv,
                                                     const __bf16* __restrict__ vtg,
                                                     __bf16* __restrict__ y) {
  const int b = blockIdx.y >> 4, h = blockIdx.y & 15;
  const int g = h >> 2;
  const int q0 = ((int)gridDim.x - 1 - (int)blockIdx.x) * 128;  // longest blocks first
  const int tid = threadIdx.x;
  const int wave = tid >> 6, lane = tid & 63;
  const int l31 = lane & 31, hi = lane >> 5;

  const __bf16* Qb = qkv + (size_t)b * Tn * 3072 + h * 128;
  const __bf16* Kb = qkv + (size_t)b * Tn * 3072 + 2048 + g * 128;
  const __bf16* Vt = vtg + (size_t)(b * 4 + g) * 128 * Tn;  // [dim][key]

  __shared__ __attribute__((aligned(16))) __bf16 Ks[2][8192];  // 2 x 16 KB
  __shared__ __attribute__((aligned(16))) __bf16 Vs[2][8192];  // 2 x 16 KB

  // Fragment-linear chunk maps (chunk c = 16B at elem offset c*8):
  //  Ks: c=(kb*8+s)*64+lane -> K[key kb*32+(lane&31)][dim s*16+(lane>>5)*8 ..+8]
  //  Vs: c=(db*4+s)*64+lane -> V^T[dim db*32+(lane&31)][key s*16+(lane>>5)*8 ..+8]
  // Staging instr i (0..3) of wave w covers chunks [i*256+w*64, +64):
  //  K: kb=i>>1, s=(i*4+w)&7 ; V: db=i, s=w. Per-lane GLOBAL source below;
  //  LDS dest is the wave-uniform chunk base (HW adds lane*16).
  const __bf16* ksrc[4];
  const __bf16* vsrc[4];
#pragma unroll
  for (int i = 0; i < 4; ++i) {
    ksrc[i] = Kb + (size_t)((i >> 1) * 32 + l31) * 3072 + ((i * 4 + wave) & 7) * 16 + hi * 8;
    vsrc[i] = Vt + (size_t)(i * 32 + l31) * Tn + wave * 16 + hi * 8;
  }

  // Q as B-operand: lane holds Q[q = q0+wave*32+l31][k-step s: s*16 + hi*8 ..+8]
  const int qg = q0 + wave * 32 + l31;
  bf16x8 qf[8];
#pragma unroll
  for (int s = 0; s < 8; ++s)
    qf[s] = *(const bf16x8*)(Qb + (size_t)qg * 3072 + s * 16 + hi * 8);

  f32x16 o[4] = {};
  float m_i = -1e30f, l_i = 0.f;
  const float kscale = 0.12752909695983215f;  // (1/sqrt(128)) * log2(e)

  // ---- prologue: stage tile 0 into buffer 0; barrier drains vmcnt(0)
#pragma unroll
  for (int i = 0; i < 4; ++i) {
    __builtin_amdgcn_global_load_lds((GLOBAL_AS void*)ksrc[i],
                                     (LDS_AS void*)(&Ks[0][(i * 256 + wave * 64) * 8]), 16, 0, 0);
    __builtin_amdgcn_global_load_lds((GLOBAL_AS void*)vsrc[i],
                                     (LDS_AS void*)(&Vs[0][(i * 256 + wave * 64) * 8]), 16, 0, 0);
    ksrc[i] += (size_t)KVB * 3072;
    vsrc[i] += KVB;
  }
  __syncthreads();

  const int ktend = q0 + 128;
  int cur = 0;
  for (int kt = 0; kt < ktend; kt += KVB) {
    // ---- issue next-tile staging into the other buffer (overlaps compute)
    if (kt + KVB < ktend) {
#pragma unroll
      for (int i = 0; i < 4; ++i) {
        __builtin_amdgcn_global_load_lds(
            (GLOBAL_AS void*)ksrc[i],
            (LDS_AS void*)(&Ks[cur ^ 1][(i * 256 + wave * 64) * 8]), 16, 0, 0);
        __builtin_amdgcn_global_load_lds(
            (GLOBAL_AS void*)vsrc[i],
            (LDS_AS void*)(&Vs[cur ^ 1][(i * 256 + wave * 64) * 8]), 16, 0, 0);
        ksrc[i] += (size_t)KVB * 3072;
        vsrc[i] += KVB;
      }
    }

    // ---- per-wave skip of fully-masked causal tiles (wave-uniform)
    if (kt <= q0 + wave * 32 + 31) {
      // S^T = K Q^T : 2 key-blocks x 8 k-steps of 32x32x16
      f32x16 sa[2] = {};
      __builtin_amdgcn_s_setprio(1);
#pragma unroll
      for (int kb = 0; kb < 2; ++kb)
#pragma unroll
        for (int s = 0; s < 8; ++s) {
          const bf16x8 kf = *(const bf16x8*)(&Ks[cur][((kb * 8 + s) * 64 + lane) * 8]);
          sa[kb] = mfma32(kf, qf[s], sa[kb]);
        }
      __builtin_amdgcn_s_setprio(0);

      // ---- softmax (log2 domain), scores fully lane-pair-local.
      // lane's keys: kt + kb*32 + (r&3)+8*(r>>2)+4*hi.
      const bool full = (kt + KVB - 1) <= (q0 + wave * 32);  // wave-uniform
      float mx = -1e30f;
      if (full) {
#pragma unroll
        for (int kb = 0; kb < 2; ++kb)
#pragma unroll
          for (int r = 0; r < 16; ++r) {
            const float v = sa[kb][r] * kscale;
            sa[kb][r] = v;
            mx = fmaxf(mx, v);
          }
      } else {
#pragma unroll
        for (int kb = 0; kb < 2; ++kb)
#pragma unroll
          for (int r = 0; r < 16; ++r) {
            const int key = kt + kb * 32 + (r & 3) + 8 * (r >> 2) + 4 * hi;
            const float v = (key <= qg) ? sa[kb][r] * kscale : -1e30f;
            sa[kb][r] = v;
            mx = fmaxf(mx, v);
          }
      }
      mx = fmaxf(mx, __shfl_xor(mx, 32));  // combine lane pair: full 64-key max
      if (__any(mx > m_i + 8.f)) {  // defer-max: rescale only on >8 growth
        const float mnew = fmaxf(m_i, mx);
        const float alpha = __builtin_amdgcn_exp2f(m_i - mnew);
        m_i = mnew;
        l_i *= alpha;
#pragma unroll
        for (int db = 0; db < 4; ++db)
#pragma unroll
          for (int r = 0; r < 16; ++r) o[db][r] *= alpha;
      }
      float ls = 0.f;
#pragma unroll
      for (int kb = 0; kb < 2; ++kb)
#pragma unroll
        for (int r = 0; r < 16; ++r) {
          const float pv = __builtin_amdgcn_exp2f(sa[kb][r] - m_i);
          sa[kb][r] = pv;
          ls += pv;
        }
      l_i += ls;  // per-lane partial (own 32 keys); pair-combined in epilogue

      // ---- assemble P^T B-operand fragments in-register.
      // pack pairs, one symmetric xor-32 exchange, hi-select per word.
      uint32_t P[2][8], X[2][8];
#pragma unroll
      for (int kb = 0; kb < 2; ++kb)
#pragma unroll
        for (int gg = 0; gg < 8; ++gg)
          P[kb][gg] = pack_bf16(sa[kb][2 * gg], sa[kb][2 * gg + 1]);
#pragma unroll
      for (int kb = 0; kb < 2; ++kb)
#pragma unroll
        for (int gg = 0; gg < 8; ++gg)
          X[kb][gg] = (uint32_t)__shfl_xor((int)P[kb][gg], 32);

      union FU { uint32_t u[4]; bf16x8 v; };
      bf16x8 pf[4];  // k-step s: keys kt + s*16 + hi*8 ..+8
#pragma unroll
      for (int kb = 0; kb < 2; ++kb) {
        FU f0, f1;
        f0.u[0] = hi ? X[kb][2] : P[kb][0];
        f0.u[1] = hi ? X[kb][3] : P[kb][1];
        f0.u[2] = hi ? P[kb][2] : X[kb][0];
        f0.u[3] = hi ? P[kb][3] : X[kb][1];
        f1.u[0] = hi ? X[kb][6] : P[kb][4];
        f1.u[1] = hi ? X[kb][7] : P[kb][5];
        f1.u[2] = hi ? P[kb][6] : X[kb][4];
        f1.u[3] = hi ? P[kb][7] : X[kb][5];
        pf[kb * 2 + 0] = f0.v;
        pf[kb * 2 + 1] = f1.v;
      }

      // ---- O^T += V^T P^T : 4 dim-blocks x 4 k-steps of 32x32x16
      __builtin_amdgcn_s_setprio(1);
#pragma unroll
      for (int db = 0; db < 4; ++db)
#pragma unroll
        for (int s = 0; s < 4; ++s) {
          const bf16x8 vf = *(const bf16x8*)(&Vs[cur][((db * 4 + s) * 64 + lane) * 8]);
          o[db] = mfma32(vf, pf[s], o[db]);
        }
      __builtin_amdgcn_s_setprio(0);
    }

    // one barrier per tile: implicit vmcnt(0) drain = next tile staged,
    // and all waves done reading buf[cur] before it is overwritten.
    __syncthreads();
    cur ^= 1;
  }

  // ---- epilogue: pair-combine l, normalize, store (O^T: row=d, col=q)
  {
    const float lt = l_i + __shfl_xor(l_i, 32);
    const float inv = 1.0f / lt;
    __bf16* yrow = y + (size_t)(b * Tn + qg) * 2048 + h * 128;
#pragma unroll
    for (int db = 0; db < 4; ++db)
#pragma unroll
      for (int g2 = 0; g2 < 4; ++g2) {
        bf16x4 ov;
#pragma unroll
        for (int j = 0; j < 4; ++j) ov[j] = (__bf16)(o[db][4 * g2 + j] * inv);
        *(bf16x4*)(yrow + db * 32 + 8 * g2 + 4 * hi) = ov;
      }
  }
}

// ---------------------------------------------------------------- launch
extern "C" void kernel_launch(void* const* d_in, const int* in_sizes, int n_in,
                              void* d_out, int out_size, void* d_ws, size_t ws_size,
                              hipStream_t stream) {
  (void)in_sizes; (void)n_in; (void)out_size; (void)ws_size;
  const float* x  = (const float*)d_in[0];
  const float* Wq = (const float*)d_in[1];
  const float* Wk = (const float*)d_in[2];
  const float* Wv = (const float*)d_in[3];
  const float* Wo = (const float*)d_in[4];
  float* out = (float*)d_out;

  __bf16* xb  = (__bf16*)d_ws;                  // [4096][2048]; y aliases after gemm1
  __bf16* y   = xb;
  __bf16* WT  = xb + (size_t)4096 * 2048;       // [3072][2048]
  __bf16* WoT = WT;                             // [2048][2048] aliases after gemm1
  __bf16* VtG = WT + (size_t)2048 * 2048;       // [8][128][2048]
  __bf16* qkv = WT + (size_t)3072 * 2048;       // [4096][3072]

  convert_f32_bf16<<<(4096 * 2048 / 4 + 255) / 256, 256, 0, stream>>>(x, xb, 4096 * 2048 / 4);
  dim3 tb(32, 8);
  transpose_f32_bf16<<<dim3(64, 64), tb, 0, stream>>>(Wq, WT, 2048, 2048);
  transpose_f32_bf16<<<dim3(16, 64), tb, 0, stream>>>(Wk, WT + (size_t)2048 * 2048, 2048, 512);
  transpose_f32_bf16<<<dim3(16, 64), tb, 0, stream>>>(Wv, WT + (size_t)2560 * 2048, 2048, 512);

  gemm_bt<<<dim3(3072 / 128, 4096 / 128), 256, 0, stream>>>(xb, WT, qkv, 2048, 3072, 0);
  rope_kernel<<<4096, 256, 0, stream>>>(qkv);

  transpose_v<<<dim3(Tn / 32, 4, 8), tb, 0, stream>>>(qkv, VtG);
  transpose_f32_bf16<<<dim3(64, 64), tb, 0, stream>>>(Wo, WoT, 2048, 2048);

  flash_attn<<<dim3(Tn / 128, 2 * 16), 256, 0, stream>>>(qkv, VtG, y);
  gemm_bt<<<dim3(2048 / 128, 4096 / 128), 256, 0, stream>>>(y, WoT, out, 2048, 2048, 1);
}